// Round 1
// baseline (954.020 us; speedup 1.0000x reference)
//
#include <hip/hip_runtime.h>

#define T_TOK 2048
#define H_DIM 2048
#define E_NUM 32
#define I_DIM 768
#define TOPK 8

typedef __attribute__((ext_vector_type(8))) _Float16 f16x8;
typedef __attribute__((ext_vector_type(4))) _Float16 f16x4;
typedef __attribute__((ext_vector_type(4))) float f32x4;

// ---------------- x fp32 -> fp16 ----------------
__global__ __launch_bounds__(256) void cvt_x_kernel(const float* __restrict__ x,
                                                    _Float16* __restrict__ xh) {
    int i = blockIdx.x * 256 + threadIdx.x;  // one f32x4 per thread
    f32x4 f = ((const f32x4*)x)[i];
    f16x4 h;
    h[0] = (_Float16)f[0]; h[1] = (_Float16)f[1];
    h[2] = (_Float16)f[2]; h[3] = (_Float16)f[3];
    ((f16x4*)xh)[i] = h;
}

// ---------------- router: logits (fp32) + top-8 + softmax ----------------
__global__ __launch_bounds__(256) void router_kernel(const float* __restrict__ x,
                                                     const float* __restrict__ gw,
                                                     int* __restrict__ sel_e,
                                                     float* __restrict__ sel_w,
                                                     int* __restrict__ counts) {
    int t = blockIdx.x;
    int tid = threadIdx.x, lane = tid & 63, wave = tid >> 6;
    __shared__ float logits[E_NUM];
    const float* xr = x + (size_t)t * H_DIM;
    float xv[32];
#pragma unroll
    for (int c = 0; c < 32; ++c) xv[c] = xr[lane + c * 64];
    for (int j = 0; j < 8; ++j) {
        int e = wave * 8 + j;
        const float* wr = gw + (size_t)e * H_DIM;
        float acc = 0.f;
#pragma unroll
        for (int c = 0; c < 32; ++c) acc += xv[c] * wr[lane + c * 64];
#pragma unroll
        for (int s = 32; s > 0; s >>= 1) acc += __shfl_xor(acc, s, 64);
        if (lane == 0) logits[e] = acc;
    }
    __syncthreads();
    if (tid == 0) {
        float lg[E_NUM];
        for (int e2 = 0; e2 < E_NUM; ++e2) lg[e2] = logits[e2];
        unsigned taken = 0;
        float sv[TOPK]; int se[TOPK];
        for (int k = 0; k < TOPK; ++k) {          // top-k, ties -> lowest index (matches lax.top_k)
            float best = -3.4e38f; int bi = 0;
            for (int e2 = 0; e2 < E_NUM; ++e2)
                if (!((taken >> e2) & 1u) && lg[e2] > best) { best = lg[e2]; bi = e2; }
            taken |= 1u << bi; sv[k] = best; se[k] = bi;
        }
        float m = sv[0], s = 0.f;
        for (int k = 0; k < TOPK; ++k) { sv[k] = expf(sv[k] - m); s += sv[k]; }
        float inv = 1.f / s;
        for (int k = 0; k < TOPK; ++k) {
            sel_e[t * TOPK + k] = se[k];
            sel_w[t * TOPK + k] = sv[k] * inv;
            atomicAdd(&counts[se[k]], 1);
        }
    }
}

// ---------------- exclusive scan over 32 expert counts ----------------
__global__ void scan_kernel(const int* __restrict__ counts, int* __restrict__ offs) {
    if (threadIdx.x == 0) {
        int s = 0;
        for (int e = 0; e < E_NUM; ++e) { offs[e] = s; s += counts[e]; }
        offs[E_NUM] = s;
    }
}

// ---------------- scatter (token,weight) pairs into per-expert lists ----------------
__global__ __launch_bounds__(256) void scatter_kernel(const int* __restrict__ sel_e,
                                                      const float* __restrict__ sel_w,
                                                      const int* __restrict__ offs,
                                                      int* __restrict__ cursor,
                                                      int* __restrict__ pair_token,
                                                      float* __restrict__ pair_w) {
    int t = blockIdx.x * 256 + threadIdx.x;
    if (t >= T_TOK) return;
    for (int k = 0; k < TOPK; ++k) {
        int e = sel_e[t * TOPK + k];
        int pos = atomicAdd(&cursor[e], 1);
        int slot = offs[e] + pos;
        pair_token[slot] = t;
        pair_w[slot] = sel_w[t * TOPK + k];
    }
}

// ---------------- mlp1: h = silu(x@Wg^T) * (x@Wu^T) * pair_w, fp16 MFMA ----------------
// grid (6 Ntiles, 16 Mtiles, 32 experts), 256 thr (4 waves, 2x2 of 64x64)
__global__ __launch_bounds__(256, 2) void mlp1_kernel(const _Float16* __restrict__ xh,
                                                      const float* __restrict__ wg,
                                                      const float* __restrict__ wu,
                                                      const int* __restrict__ offs,
                                                      const int* __restrict__ pair_token,
                                                      const float* __restrict__ pair_w,
                                                      _Float16* __restrict__ h_buf) {
    int e = blockIdx.z, mt = blockIdx.y, nt = blockIdx.x;
    int base = offs[e], cnt = offs[e + 1] - base;
    if (mt * 128 >= cnt) return;
    int tid = threadIdx.x, lane = tid & 63, wave = tid >> 6;

    __shared__ _Float16 As[128 * 40];   // pad stride 40 halves: 2-way-max banks
    __shared__ _Float16 Bg[128 * 40];
    __shared__ _Float16 Bu[128 * 40];

    // A staging: 512 chunks of 8 halves; thread -> chunks {tid, tid+256}
    const _Float16* aSrc[2]; int aDst[2];
#pragma unroll
    for (int i = 0; i < 2; ++i) {
        int c = tid + i * 256;
        int row = c >> 2, col8 = c & 3;
        int g = mt * 128 + row;
        int tok = (g < cnt) ? pair_token[base + g] : pair_token[base];
        aSrc[i] = xh + (size_t)tok * H_DIM + col8 * 8;
        aDst[i] = row * 40 + col8 * 8;
    }
    // B staging: 1024 chunks of 4 floats per matrix
    const float* gSrc[4]; const float* uSrc[4]; int bDst[4];
#pragma unroll
    for (int i = 0; i < 4; ++i) {
        int c = tid + i * 256;
        int row = c >> 3, col4 = c & 7;
        size_t wOff = ((size_t)e * I_DIM + nt * 128 + row) * H_DIM + col4 * 4;
        gSrc[i] = wg + wOff; uSrc[i] = wu + wOff;
        bDst[i] = row * 40 + col4 * 4;
    }

    const f32x4 zero = {0.f, 0.f, 0.f, 0.f};
    f32x4 accg[4][4], accu[4][4];
#pragma unroll
    for (int mi = 0; mi < 4; ++mi)
#pragma unroll
        for (int ni = 0; ni < 4; ++ni) { accg[mi][ni] = zero; accu[mi][ni] = zero; }

    int m16 = lane & 15, quad = lane >> 4, wm = wave >> 1, wn = wave & 1;

    for (int k0 = 0; k0 < H_DIM; k0 += 32) {
#pragma unroll
        for (int i = 0; i < 2; ++i)
            *(f16x8*)&As[aDst[i]] = *(const f16x8*)(aSrc[i] + k0);
#pragma unroll
        for (int i = 0; i < 4; ++i) {
            f32x4 fg = *(const f32x4*)(gSrc[i] + k0);
            f32x4 fu = *(const f32x4*)(uSrc[i] + k0);
            f16x4 hg, hu;
#pragma unroll
            for (int q = 0; q < 4; ++q) { hg[q] = (_Float16)fg[q]; hu[q] = (_Float16)fu[q]; }
            *(f16x4*)&Bg[bDst[i]] = hg;
            *(f16x4*)&Bu[bDst[i]] = hu;
        }
        __syncthreads();
        f16x8 a[4], bg[4], bu[4];
#pragma unroll
        for (int mi = 0; mi < 4; ++mi)
            a[mi] = *(const f16x8*)&As[(wm * 64 + mi * 16 + m16) * 40 + quad * 8];
#pragma unroll
        for (int ni = 0; ni < 4; ++ni) {
            int r = (wn * 64 + ni * 16 + m16) * 40 + quad * 8;
            bg[ni] = *(const f16x8*)&Bg[r];
            bu[ni] = *(const f16x8*)&Bu[r];
        }
#pragma unroll
        for (int mi = 0; mi < 4; ++mi)
#pragma unroll
            for (int ni = 0; ni < 4; ++ni) {
                accg[mi][ni] = __builtin_amdgcn_mfma_f32_16x16x32_f16(a[mi], bg[ni], accg[mi][ni], 0, 0, 0);
                accu[mi][ni] = __builtin_amdgcn_mfma_f32_16x16x32_f16(a[mi], bu[ni], accu[mi][ni], 0, 0, 0);
            }
        __syncthreads();
    }

    // epilogue: silu(g)*u*pair_w -> h_buf (fp16). C/D: col=lane&15, row=quad*4+reg
#pragma unroll
    for (int mi = 0; mi < 4; ++mi) {
#pragma unroll
        for (int reg = 0; reg < 4; ++reg) {
            int rloc = wm * 64 + mi * 16 + quad * 4 + reg;
            int g = mt * 128 + rloc;
            if (g >= cnt) continue;
            int slot = base + g;
            float pw = pair_w[slot];
#pragma unroll
            for (int ni = 0; ni < 4; ++ni) {
                int col = nt * 128 + wn * 64 + ni * 16 + m16;
                float gv = accg[mi][ni][reg];
                float uv = accu[mi][ni][reg];
                float hv = (gv / (1.f + expf(-gv))) * uv * pw;
                h_buf[(size_t)slot * I_DIM + col] = (_Float16)hv;
            }
        }
    }
}

// ---------------- mlp2: out[t] += h_slot @ Wd^T (scatter-add) ----------------
// grid (16 Ntiles, 16 Mtiles, 32 experts)
__global__ __launch_bounds__(256, 2) void mlp2_kernel(const _Float16* __restrict__ h_buf,
                                                      const float* __restrict__ wd,
                                                      const int* __restrict__ offs,
                                                      const int* __restrict__ pair_token,
                                                      float* __restrict__ out) {
    int e = blockIdx.z, mt = blockIdx.y, nt = blockIdx.x;
    int base = offs[e], cnt = offs[e + 1] - base;
    if (mt * 128 >= cnt) return;
    int tid = threadIdx.x, lane = tid & 63, wave = tid >> 6;

    __shared__ _Float16 As[128 * 40];
    __shared__ _Float16 Bs[128 * 40];

    const _Float16* aSrc[2]; int aDst[2];
#pragma unroll
    for (int i = 0; i < 2; ++i) {
        int c = tid + i * 256;
        int row = c >> 2, col8 = c & 3;
        int g = mt * 128 + row;
        int slot = (g < cnt) ? (base + g) : base;  // clamp: avoid OOB reads past h_buf
        aSrc[i] = h_buf + (size_t)slot * I_DIM + col8 * 8;
        aDst[i] = row * 40 + col8 * 8;
    }
    const float* bSrc[4]; int bDst[4];
#pragma unroll
    for (int i = 0; i < 4; ++i) {
        int c = tid + i * 256;
        int row = c >> 3, col4 = c & 7;
        bSrc[i] = wd + ((size_t)e * H_DIM + nt * 128 + row) * I_DIM + col4 * 4;
        bDst[i] = row * 40 + col4 * 4;
    }

    const f32x4 zero = {0.f, 0.f, 0.f, 0.f};
    f32x4 acc[4][4];
#pragma unroll
    for (int mi = 0; mi < 4; ++mi)
#pragma unroll
        for (int ni = 0; ni < 4; ++ni) acc[mi][ni] = zero;

    int m16 = lane & 15, quad = lane >> 4, wm = wave >> 1, wn = wave & 1;

    for (int k0 = 0; k0 < I_DIM; k0 += 32) {
#pragma unroll
        for (int i = 0; i < 2; ++i)
            *(f16x8*)&As[aDst[i]] = *(const f16x8*)(aSrc[i] + k0);
#pragma unroll
        for (int i = 0; i < 4; ++i) {
            f32x4 f = *(const f32x4*)(bSrc[i] + k0);
            f16x4 h;
#pragma unroll
            for (int q = 0; q < 4; ++q) h[q] = (_Float16)f[q];
            *(f16x4*)&Bs[bDst[i]] = h;
        }
        __syncthreads();
        f16x8 a[4], b[4];
#pragma unroll
        for (int mi = 0; mi < 4; ++mi)
            a[mi] = *(const f16x8*)&As[(wm * 64 + mi * 16 + m16) * 40 + quad * 8];
#pragma unroll
        for (int ni = 0; ni < 4; ++ni)
            b[ni] = *(const f16x8*)&Bs[(wn * 64 + ni * 16 + m16) * 40 + quad * 8];
#pragma unroll
        for (int mi = 0; mi < 4; ++mi)
#pragma unroll
            for (int ni = 0; ni < 4; ++ni)
                acc[mi][ni] = __builtin_amdgcn_mfma_f32_16x16x32_f16(a[mi], b[ni], acc[mi][ni], 0, 0, 0);
        __syncthreads();
    }

#pragma unroll
    for (int mi = 0; mi < 4; ++mi) {
#pragma unroll
        for (int reg = 0; reg < 4; ++reg) {
            int rloc = wm * 64 + mi * 16 + quad * 4 + reg;
            int g = mt * 128 + rloc;
            if (g >= cnt) continue;
            int t = pair_token[base + g];
#pragma unroll
            for (int ni = 0; ni < 4; ++ni) {
                int col = nt * 128 + wn * 64 + ni * 16 + m16;
                atomicAdd(&out[(size_t)t * H_DIM + col], acc[mi][ni][reg]);
            }
        }
    }
}

extern "C" void kernel_launch(void* const* d_in, const int* in_sizes, int n_in,
                              void* d_out, int out_size, void* d_ws, size_t ws_size,
                              hipStream_t stream) {
    const float* x  = (const float*)d_in[0];
    const float* gw = (const float*)d_in[1];
    const float* wg = (const float*)d_in[2];
    const float* wu = (const float*)d_in[3];
    const float* wd = (const float*)d_in[4];
    float* out = (float*)d_out;

    char* ws = (char*)d_ws;
    int*      sel_e      = (int*)(ws + 0);          // 64 KB
    float*    sel_w      = (float*)(ws + 65536);    // 64 KB
    int*      counts     = (int*)(ws + 131072);     // 128 B
    int*      cursor     = (int*)(ws + 131200);     // 128 B
    int*      offs       = (int*)(ws + 131328);     // 33*4 B
    int*      pair_token = (int*)(ws + 131584);     // 64 KB
    float*    pair_w     = (float*)(ws + 197120);   // 64 KB
    _Float16* xh         = (_Float16*)(ws + 262656);   // 8 MB
    _Float16* h_buf      = (_Float16*)(ws + 8651264);  // 24 MB

    hipMemsetAsync(ws + 131072, 0, 256, stream);                       // counts + cursor
    hipMemsetAsync(d_out, 0, (size_t)T_TOK * H_DIM * sizeof(float), stream);

    cvt_x_kernel<<<(T_TOK * H_DIM / 4) / 256, 256, 0, stream>>>(x, xh);
    router_kernel<<<T_TOK, 256, 0, stream>>>(x, gw, sel_e, sel_w, counts);
    scan_kernel<<<1, 64, 0, stream>>>(counts, offs);
    scatter_kernel<<<T_TOK / 256, 256, 0, stream>>>(sel_e, sel_w, offs, cursor, pair_token, pair_w);
    mlp1_kernel<<<dim3(6, 16, 32), 256, 0, stream>>>(xh, wg, wu, offs, pair_token, pair_w, h_buf);
    mlp2_kernel<<<dim3(16, 16, 32), 256, 0, stream>>>(h_buf, wd, offs, pair_token, out);
}